// Round 9
// baseline (291.100 us; speedup 1.0000x reference)
//
#include <hip/hip_runtime.h>

#define D 128
#define EPS 1e-5f
#define SCAN_CHUNK 2048
#define FB_EPB 8   // edges per thread in bfill (512 threads -> 4096 edges/block)

typedef unsigned int uint;
typedef __attribute__((ext_vector_type(4))) float f32x4;
typedef __attribute__((ext_vector_type(8))) short s16x8;

// ---- bf16 pack/unpack helpers (RTNE) ---------------------------------------
__device__ __forceinline__ uint pack_bf16(float a, float b)
{
    uint ua = __float_as_uint(a);
    uint ub = __float_as_uint(b);
    ua += 0x7FFFu + ((ua >> 16) & 1u);
    ub += 0x7FFFu + ((ub >> 16) & 1u);
    return (ua >> 16) | (ub & 0xFFFF0000u);
}
__device__ __forceinline__ float bf_lo(uint v) { return __uint_as_float(v << 16); }
__device__ __forceinline__ float bf_hi(uint v) { return __uint_as_float(v & 0xFFFF0000u); }

// ---- prep: x->xb (bf16) + wb1/wb2 (MFMA B-frag order) + degree histogram ----
__global__ void prep_kernel(const float* __restrict__ x, uint* __restrict__ xb, int ncvt,
                            const float* __restrict__ w1l, const float* __restrict__ w1r,
                            const float* __restrict__ w2l, const float* __restrict__ w2r,
                            uint* __restrict__ wb1, uint* __restrict__ wb2,
                            const int* __restrict__ dst, int* __restrict__ deg, int E)
{
    int idx = blockIdx.x * 256 + threadIdx.x;
    if (idx < ncvt) {
        float4 v = ((const float4*)x)[idx];
        uint2 o;
        o.x = pack_bf16(v.x, v.y);
        o.y = pack_bf16(v.z, v.w);
        ((uint2*)xb)[idx] = o;
    } else if (idx < ncvt + 8192) {
        int r = idx - ncvt;          // 0..8191
        int layer = r >> 12;
        int rem = r & 4095;
        int lane = rem & 63;
        int knt = rem >> 6;
        int kstep = knt >> 3, nt = knt & 7;
        int nn = nt * 16 + (lane & 15);
        int kbase = kstep * 32 + (lane >> 4) * 8;
        const float* wl = layer ? w2l : w1l;
        const float* wr = layer ? w2r : w1r;
        uint* wb = layer ? wb2 : wb1;
        float v[8];
#pragma unroll
        for (int j = 0; j < 8; j++) {
            int k = kbase + j;
            v[j] = (k < D) ? wl[nn * D + k] : wr[nn * D + (k - D)];
        }
        uint4 o;
        o.x = pack_bf16(v[0], v[1]);
        o.y = pack_bf16(v[2], v[3]);
        o.z = pack_bf16(v[4], v[5]);
        o.w = pack_bf16(v[6], v[7]);
        ((uint4*)wb)[(kstep * 8 + nt) * 64 + lane] = o;
    } else {
        int e = idx - (ncvt + 8192);
        if (e < E) atomicAdd(&deg[dst[e]], 1);
    }
}

// ---- CSR build --------------------------------------------------------------
__global__ __launch_bounds__(256) void scanA_kernel(const int* __restrict__ deg,
                                                    int* __restrict__ bsum, int n)
{
    __shared__ int red[256];
    int base = blockIdx.x * SCAN_CHUNK;
    int s = 0;
    for (int i = threadIdx.x; i < SCAN_CHUNK; i += 256) {
        int idx = base + i;
        if (idx < n) s += deg[idx];
    }
    red[threadIdx.x] = s;
    __syncthreads();
    for (int off = 128; off > 0; off >>= 1) {
        if (threadIdx.x < off) red[threadIdx.x] += red[threadIdx.x + off];
        __syncthreads();
    }
    if (threadIdx.x == 0) bsum[blockIdx.x] = red[0];
}

__global__ void scanB_kernel(int* __restrict__ bsum, int nb)
{
    int t = threadIdx.x;
    int v = (t < nb) ? bsum[t] : 0;
    for (int off = 1; off < 64; off <<= 1) {
        int u = __shfl_up(v, off);
        if (t >= off) v += u;
    }
    int ex = __shfl_up(v, 1);
    if (t == 0) ex = 0;
    if (t < nb) bsum[t] = ex;
}

// writes rowptr; also seeds line-padded bucket cursors bcur[b*16] = rowptr[b*512]
__global__ __launch_bounds__(256) void scanC_kernel(const int* __restrict__ deg,
                                                    const int* __restrict__ bsum,
                                                    int* __restrict__ rowptr,
                                                    int* __restrict__ bcur, int n, int E)
{
    __shared__ int tsum[256];
    int t = threadIdx.x;
    int tb = blockIdx.x * SCAN_CHUNK + t * 8;
    int v[8];
    int s = 0;
#pragma unroll
    for (int k = 0; k < 8; k++) {
        int idx = tb + k;
        v[k] = (idx < n) ? deg[idx] : 0;
        s += v[k];
    }
    tsum[t] = s;
    __syncthreads();
    for (int off = 1; off < 256; off <<= 1) {
        int u = (t >= off) ? tsum[t - off] : 0;
        __syncthreads();
        tsum[t] += u;
        __syncthreads();
    }
    int run = bsum[blockIdx.x] + tsum[t] - s;
#pragma unroll
    for (int k = 0; k < 8; k++) {
        int idx = tb + k;
        if (idx < n) {
            rowptr[idx] = run;
            if ((idx & 511) == 0) bcur[(idx >> 9) * 16] = run;
            run += v[k];
        }
    }
    if (blockIdx.x == 0 && t == 0) rowptr[n] = E;
}

// ---- bucketed fill phase 1: edges -> ebuf, bucket-contiguous ---------------
__global__ __launch_bounds__(512) void bfill_kernel(const int* __restrict__ src,
                                                    const int* __restrict__ dst,
                                                    int* __restrict__ bcur,
                                                    uint2* __restrict__ ebuf,
                                                    int E, int nbuck)
{
    __shared__ int cnt[128], base[128];
    int t = threadIdx.x;
    if (t < 128) cnt[t] = 0;
    __syncthreads();
    int e0 = blockIdx.x * (512 * FB_EPB);
    int s[FB_EPB], d[FB_EPB], loc[FB_EPB];
#pragma unroll
    for (int k = 0; k < FB_EPB; k++) {
        int e = e0 + k * 512 + t;
        if (e < E) {
            s[k] = src[e];
            d[k] = dst[e];
            loc[k] = atomicAdd(&cnt[d[k] >> 9], 1);
        }
    }
    __syncthreads();
    if (t < nbuck) base[t] = atomicAdd(&bcur[t * 16], cnt[t]);
    __syncthreads();
#pragma unroll
    for (int k = 0; k < FB_EPB; k++) {
        int e = e0 + k * 512 + t;
        if (e < E) {
            int b = d[k] >> 9;
            ebuf[base[b] + loc[k]] = make_uint2((uint)s[k], (uint)d[k]);
        }
    }
}

// ---- bucketed fill phase 2: ebuf -> col via LDS cursors (one block/bucket) -
__global__ __launch_bounds__(512) void pfill_kernel(const int* __restrict__ rowptr,
                                                    const uint2* __restrict__ ebuf,
                                                    int* __restrict__ col, int n)
{
    __shared__ int lcur[512];
    int t = threadIdx.x;
    int nb = blockIdx.x << 9;
    int ncnt = min(512, n - nb);
    if (t < ncnt) lcur[t] = rowptr[nb + t];
    __syncthreads();
    int e0 = rowptr[nb];
    int e1 = rowptr[min(nb + 512, n)];
    for (int i = e0 + t; i < e1; i += 512) {
        uint2 ed = ebuf[i];
        int p = atomicAdd(&lcur[(int)ed.y - nb], 1);
        col[p] = (int)ed.x;
    }
}

// ---- gather aggregation: predicated 32-neighbor superbatches ---------------
// Wave per node; lane = sub*16 + l16. Each superbatch issues 8 rounds x 4 subs
// = 32 row-gathers unconditionally (clamped index); invalid contributions are
// zeroed AFTER BN+ReLU, so one latency window covers deg<=32 (~98% of nodes).
template<bool BN>
__global__ __launch_bounds__(256) void agg_kernel(const int* __restrict__ rowptr,
                                                  const int* __restrict__ col,
                                                  const uint* __restrict__ featb,
                                                  const float* __restrict__ scsh,
                                                  uint* __restrict__ aggb, int n)
{
    int node = blockIdx.x * 4 + (threadIdx.x >> 6);
    if (node >= n) return;
    int lane = threadIdx.x & 63;
    int sub = lane >> 4, l16 = lane & 15;
    int r0 = rowptr[node], r1 = rowptr[node + 1];
    uint4* out4 = (uint4*)aggb;
    if (r0 == r1) {
        if (lane < 16) out4[(size_t)node * 16 + l16] = make_uint4(0, 0, 0, 0);
        return;
    }
    float sc[8], sh[8];
    if (BN) {
        float4 s0 = ((const float4*)scsh)[l16 * 2];
        float4 s1 = ((const float4*)scsh)[l16 * 2 + 1];
        float4 t0 = ((const float4*)scsh)[32 + l16 * 2];
        float4 t1 = ((const float4*)scsh)[32 + l16 * 2 + 1];
        sc[0] = s0.x; sc[1] = s0.y; sc[2] = s0.z; sc[3] = s0.w;
        sc[4] = s1.x; sc[5] = s1.y; sc[6] = s1.z; sc[7] = s1.w;
        sh[0] = t0.x; sh[1] = t0.y; sh[2] = t0.z; sh[3] = t0.w;
        sh[4] = t1.x; sh[5] = t1.y; sh[6] = t1.z; sh[7] = t1.w;
    }
    float acc[8] = {0.f, 0.f, 0.f, 0.f, 0.f, 0.f, 0.f, 0.f};
    const uint4* fb = (const uint4*)featb;
    int last = r1 - 1;

    for (int i = r0; i < r1; i += 32) {
        uint4 v[8];
#pragma unroll
        for (int r = 0; r < 8; r++) {
            int idx = i + r * 4 + sub;
            int c = col[min(idx, last)];
            v[r] = fb[(size_t)c * 16 + l16];
        }
#pragma unroll
        for (int r = 0; r < 8; r++) {
            bool valid = (i + r * 4 + sub) < r1;
            uint4 u = v[r];
            float e[8] = {bf_lo(u.x), bf_hi(u.x), bf_lo(u.y), bf_hi(u.y),
                          bf_lo(u.z), bf_hi(u.z), bf_lo(u.w), bf_hi(u.w)};
#pragma unroll
            for (int j = 0; j < 8; j++) {
                float t = e[j];
                if (BN) t = fmaxf(t * sc[j] + sh[j], 0.f);
                acc[j] += valid ? t : 0.f;
            }
        }
    }
#pragma unroll
    for (int j = 0; j < 8; j++) {
        acc[j] += __shfl_down(acc[j], 32);
        acc[j] += __shfl_down(acc[j], 16);
    }
    if (lane < 16) {
        float inv = 1.0f / (float)(r1 - r0);
        uint4 o;
        o.x = pack_bf16(acc[0] * inv, acc[1] * inv);
        o.y = pack_bf16(acc[2] * inv, acc[3] * inv);
        o.z = pack_bf16(acc[4] * inv, acc[5] * inv);
        o.w = pack_bf16(acc[6] * inv, acc[7] * inv);
        out4[(size_t)node * 16 + l16] = o;
    }
}

// ---- MFMA conv --------------------------------------------------------------
// FUSE1: write bf16 hb + per-block BN-stat partials (NO global atomics).
// BNP2: apply BN+ReLU inline to the p2 (root) A-fragments; write fp32 out.
#define TSTRIDE 132
template<bool FUSE1, bool BNP2>
__global__ __launch_bounds__(256) void conv_kernel(
    const uint* __restrict__ p1b, const uint* __restrict__ p2b,
    const uint* __restrict__ wb, const float* __restrict__ bias,
    const float* __restrict__ scsh, float* __restrict__ outf,
    uint* __restrict__ outb, float* __restrict__ pstats, int n)
{
    extern __shared__ float smem[];   // FUSE1: tile[64][TSTRIDE]; BNP2: scs[256]
    float* tile = smem;
    float* scs = smem;
    int w = threadIdx.x >> 6, lane = threadIdx.x & 63;
    int quad = lane >> 4, l15 = lane & 15;
    int nb = blockIdx.x * 64;

    if (BNP2) {
        scs[threadIdx.x] = scsh[threadIdx.x];
        __syncthreads();
    }

    const uint4* p1 = (const uint4*)p1b;
    const uint4* p2 = (const uint4*)p2b;
    const uint4* wv = (const uint4*)wb;

    uint4 B[8][2];
    int nt0 = w * 2;
#pragma unroll
    for (int ks = 0; ks < 8; ks++) {
#pragma unroll
        for (int t = 0; t < 2; t++)
            B[ks][t] = wv[(ks * 8 + nt0 + t) * 64 + lane];
    }

    float bv0 = bias[nt0 * 16 + l15];
    float bv1 = bias[nt0 * 16 + 16 + l15];

    for (int rt = 0; rt < 4; rt++) {
        int node = nb + rt * 16 + l15;
        int nc = min(node, n - 1);
        uint4 A[8];
#pragma unroll
        for (int ks = 0; ks < 4; ks++) A[ks] = p1[(size_t)nc * 16 + ks * 4 + quad];
#pragma unroll
        for (int ks = 0; ks < 4; ks++) A[ks + 4] = p2[(size_t)nc * 16 + ks * 4 + quad];

        if (BNP2) {
#pragma unroll
            for (int ks = 4; ks < 8; ks++) {
                int c0 = (ks - 4) * 32 + quad * 8;
                uint4 u = A[ks];
                float e[8] = {bf_lo(u.x), bf_hi(u.x), bf_lo(u.y), bf_hi(u.y),
                              bf_lo(u.z), bf_hi(u.z), bf_lo(u.w), bf_hi(u.w)};
#pragma unroll
                for (int j = 0; j < 8; j++)
                    e[j] = fmaxf(e[j] * scs[c0 + j] + scs[128 + c0 + j], 0.f);
                u.x = pack_bf16(e[0], e[1]);
                u.y = pack_bf16(e[2], e[3]);
                u.z = pack_bf16(e[4], e[5]);
                u.w = pack_bf16(e[6], e[7]);
                A[ks] = u;
            }
        }

        f32x4 acc0 = {bv0, bv0, bv0, bv0};
        f32x4 acc1 = {bv1, bv1, bv1, bv1};
#pragma unroll
        for (int ks = 0; ks < 8; ks++) {
            s16x8 a = *(s16x8*)&A[ks];
            acc0 = __builtin_amdgcn_mfma_f32_16x16x32_bf16(a, *(s16x8*)&B[ks][0], acc0, 0, 0, 0);
            acc1 = __builtin_amdgcn_mfma_f32_16x16x32_bf16(a, *(s16x8*)&B[ks][1], acc1, 0, 0, 0);
        }
        // C/D: col = lane&15, row = quad*4 + reg
        int row0 = nb + rt * 16 + quad * 4;
        int colbase = nt0 * 16 + l15;
        if (FUSE1) {
            int rloc0 = rt * 16 + quad * 4;
#pragma unroll
            for (int reg = 0; reg < 4; reg++) {
                bool ok = (row0 + reg) < n;
                tile[(rloc0 + reg) * TSTRIDE + colbase]      = ok ? acc0[reg] : 0.f;
                tile[(rloc0 + reg) * TSTRIDE + colbase + 16] = ok ? acc1[reg] : 0.f;
            }
        } else {
#pragma unroll
            for (int reg = 0; reg < 4; reg++) {
                int row = row0 + reg;
                if (row < n) {
                    outf[(size_t)row * D + colbase] = acc0[reg];
                    outf[(size_t)row * D + colbase + 16] = acc1[reg];
                }
            }
        }
    }

    if (FUSE1) {
        __syncthreads();
        // per-block column partial sums -> pstats (coalesced, no atomics)
        int colj = threadIdx.x & 127, half = threadIdx.x >> 7;
        float s = 0.f, ss = 0.f;
        for (int r = half * 32; r < half * 32 + 32; r++) {
            float v = tile[r * TSTRIDE + colj];
            s += v;
            ss += v * v;
        }
        float* pb = pstats + (size_t)blockIdx.x * 512 + half * 256;
        pb[colj] = s;
        pb[128 + colj] = ss;
        // pack tile -> bf16 hb
        uint4* ob4 = (uint4*)outb;
#pragma unroll
        for (int q4 = 0; q4 < 4; q4++) {
            int idx = q4 * 256 + threadIdx.x;   // 0..1023
            int r = idx >> 4, q = idx & 15;
            int row = nb + r;
            if (row < n) {
                float* tr = &tile[r * TSTRIDE + q * 8];
                uint4 o;
                o.x = pack_bf16(tr[0], tr[1]);
                o.y = pack_bf16(tr[2], tr[3]);
                o.z = pack_bf16(tr[4], tr[5]);
                o.w = pack_bf16(tr[6], tr[7]);
                ob4[(size_t)row * 16 + q] = o;
            }
        }
    }
}

// ---- reduce per-block stat partials into stats[256] ------------------------
__global__ __launch_bounds__(256) void reduce_kernel(const float* __restrict__ pstats,
                                                     float* __restrict__ stats, int nparts)
{
    int j = threadIdx.x;
    int chunk = (nparts + gridDim.x - 1) / gridDim.x;
    int p0 = blockIdx.x * chunk;
    int p1 = min(p0 + chunk, nparts);
    float s = 0.f;
    for (int p = p0; p < p1; p++) s += pstats[(size_t)p * 256 + j];
    unsafeAtomicAdd(&stats[j], s);
}

// ---- BN scale/shift from stats ---------------------------------------------
__global__ void bnfin_kernel(const float* __restrict__ stats, const float* __restrict__ gamma,
                             const float* __restrict__ beta, float* __restrict__ scsh, float n_inv)
{
    int j = threadIdx.x;
    float mean = stats[j] * n_inv;
    float var = fmaxf(stats[128 + j] * n_inv - mean * mean, 0.f);
    float sc = gamma[j] * rsqrtf(var + EPS);
    scsh[j] = sc;
    scsh[128 + j] = beta[j] - mean * sc;
}

extern "C" void kernel_launch(void* const* d_in, const int* in_sizes, int n_in,
                              void* d_out, int out_size, void* d_ws, size_t ws_size,
                              hipStream_t stream)
{
    const float* x     = (const float*)d_in[0];
    const int*   ei    = (const int*)d_in[1];
    const float* w1_l  = (const float*)d_in[2];
    const float* b1_l  = (const float*)d_in[3];
    const float* w1_r  = (const float*)d_in[4];
    const float* w2_l  = (const float*)d_in[5];
    const float* b2_l  = (const float*)d_in[6];
    const float* w2_r  = (const float*)d_in[7];
    const float* gamma = (const float*)d_in[8];
    const float* beta  = (const float*)d_in[9];

    int N = in_sizes[0] / D;
    int E = in_sizes[1] / 2;
    const int* src = ei;
    const int* dst = ei + E;

    int cblocks = (N + 63) / 64;
    int nbuck   = (N + 511) >> 9;

    // workspace layout:
    // uints: aggb[N*64] | xb[N*64] | hb[N*64] | wb1[16384] | wb2[16384]
    // uint2: ebuf[E]
    // floats: stats[256] | scsh[256] | pstats[cblocks*512]
    // ints: deg[N] | rowptr[N+1] | col[E] | bsum[64] | bcur[128*16]
    uint*  aggb   = (uint*)d_ws;
    uint*  xb     = aggb + (size_t)N * 64;
    uint*  hb     = xb + (size_t)N * 64;
    uint*  wb1    = hb + (size_t)N * 64;
    uint*  wb2    = wb1 + 16384;
    uint2* ebuf   = (uint2*)(wb2 + 16384);
    float* stats  = (float*)(ebuf + E);
    float* scsh   = stats + 256;
    float* pstats = scsh + 256;
    int*   deg    = (int*)(pstats + (size_t)cblocks * 512);
    int*   rowptr = deg + N;
    int*   col    = rowptr + N + 1;
    int*   bsum   = col + E;
    int*   bcur   = bsum + 64;

    hipMemsetAsync(deg, 0, (size_t)N * sizeof(int), stream);
    hipMemsetAsync(stats, 0, 256 * sizeof(float), stream);

    int ncvt = N * 32;
    int pblocks = (ncvt + 8192 + E + 255) / 256;
    prep_kernel<<<pblocks, 256, 0, stream>>>(x, xb, ncvt, w1_l, w1_r, w2_l, w2_r,
                                             wb1, wb2, dst, deg, E);

    int ablocks  = (N + 3) / 4;
    int bfblocks = (E + 4095) / 4096;
    int nscan    = (N + SCAN_CHUNK - 1) / SCAN_CHUNK;

    // CSR build (shared by both layers)
    scanA_kernel<<<nscan, 256, 0, stream>>>(deg, bsum, N);
    scanB_kernel<<<1, 64, 0, stream>>>(bsum, nscan);
    scanC_kernel<<<nscan, 256, 0, stream>>>(deg, bsum, rowptr, bcur, N, E);
    bfill_kernel<<<bfblocks, 512, 0, stream>>>(src, dst, bcur, ebuf, E, nbuck);
    pfill_kernel<<<nbuck, 512, 0, stream>>>(rowptr, ebuf, col, N);

    // layer 1: agg + conv (conv writes bf16 hb and per-block BN-stat partials)
    agg_kernel<false><<<ablocks, 256, 0, stream>>>(rowptr, col, xb, nullptr, aggb, N);
    conv_kernel<true, false><<<cblocks, 256, 64 * TSTRIDE * 4, stream>>>(
        aggb, xb, wb1, b1_l, nullptr, nullptr, hb, pstats, N);

    // reduce partials, then BN scale/shift
    reduce_kernel<<<32, 256, 0, stream>>>(pstats, stats, cblocks * 2);
    bnfin_kernel<<<1, 128, 0, stream>>>(stats, gamma, beta, scsh, 1.0f / (float)N);

    // layer 2: agg applies BN+ReLU inline; conv applies BN+ReLU to root term
    agg_kernel<true><<<ablocks, 256, 0, stream>>>(rowptr, col, hb, scsh, aggb, N);
    conv_kernel<false, true><<<cblocks, 256, 256 * 4, stream>>>(
        aggb, hb, wb2, b2_l, scsh, (float*)d_out, nullptr, nullptr, N);
}

// Round 10
// 265.186 us; speedup vs baseline: 1.0977x; 1.0977x over previous
//
#include <hip/hip_runtime.h>

#define D 128
#define EPS 1e-5f
#define FB_EPB 8   // edges per thread in bcount/bscatter (512 thr -> 4096 edges/block)

typedef unsigned int uint;
typedef __attribute__((ext_vector_type(4))) float f32x4;
typedef __attribute__((ext_vector_type(8))) short s16x8;

// ---- bf16 pack/unpack helpers (RTNE) ---------------------------------------
__device__ __forceinline__ uint pack_bf16(float a, float b)
{
    uint ua = __float_as_uint(a);
    uint ub = __float_as_uint(b);
    ua += 0x7FFFu + ((ua >> 16) & 1u);
    ub += 0x7FFFu + ((ub >> 16) & 1u);
    return (ua >> 16) | (ub & 0xFFFF0000u);
}
__device__ __forceinline__ float bf_lo(uint v) { return __uint_as_float(v << 16); }
__device__ __forceinline__ float bf_hi(uint v) { return __uint_as_float(v & 0xFFFF0000u); }

// ---- prep: x -> xb (bf16) AND wb1/wb2 (bf16, MFMA B-fragment order) --------
__global__ void prep_kernel(const float* __restrict__ x, uint* __restrict__ xb, int ncvt,
                            const float* __restrict__ w1l, const float* __restrict__ w1r,
                            const float* __restrict__ w2l, const float* __restrict__ w2r,
                            uint* __restrict__ wb1, uint* __restrict__ wb2)
{
    int idx = blockIdx.x * 256 + threadIdx.x;
    if (idx < ncvt) {
        float4 v = ((const float4*)x)[idx];
        uint2 o;
        o.x = pack_bf16(v.x, v.y);
        o.y = pack_bf16(v.z, v.w);
        ((uint2*)xb)[idx] = o;
    } else if (idx < ncvt + 8192) {
        int r = idx - ncvt;          // 0..8191
        int layer = r >> 12;
        int rem = r & 4095;
        int lane = rem & 63;
        int knt = rem >> 6;
        int kstep = knt >> 3, nt = knt & 7;
        int nn = nt * 16 + (lane & 15);
        int kbase = kstep * 32 + (lane >> 4) * 8;
        const float* wl = layer ? w2l : w1l;
        const float* wr = layer ? w2r : w1r;
        uint* wb = layer ? wb2 : wb1;
        float v[8];
#pragma unroll
        for (int j = 0; j < 8; j++) {
            int k = kbase + j;
            v[j] = (k < D) ? wl[nn * D + k] : wr[nn * D + (k - D)];
        }
        uint4 o;
        o.x = pack_bf16(v[0], v[1]);
        o.y = pack_bf16(v[2], v[3]);
        o.z = pack_bf16(v[4], v[5]);
        o.w = pack_bf16(v[6], v[7]);
        ((uint4*)wb)[(kstep * 8 + nt) * 64 + lane] = o;
    }
}

// ---- radix CSR phase 1: per-(block,bucket) edge counts ----------------------
// bucket = dst>>9. bcnt layout is bucket-major: bcnt[b*nblk + blk].
__global__ __launch_bounds__(512) void bcount_kernel(const int* __restrict__ dst,
                                                     int* __restrict__ bcnt,
                                                     int E, int nblk, int nbuck)
{
    __shared__ int cnt[128];
    int t = threadIdx.x;
    if (t < 128) cnt[t] = 0;
    __syncthreads();
    int e0 = blockIdx.x * (512 * FB_EPB);
#pragma unroll
    for (int k = 0; k < FB_EPB; k++) {
        int e = e0 + k * 512 + t;
        if (e < E) atomicAdd(&cnt[dst[e] >> 9], 1);
    }
    __syncthreads();
    if (t < nbuck) bcnt[t * nblk + blockIdx.x] = cnt[t];
}

// ---- radix CSR phase 2: single-block exclusive scan of bcnt[M], append total
__global__ __launch_bounds__(1024) void bscan_kernel(int* __restrict__ bcnt, int M)
{
    __shared__ int sums[1024];
    int t = threadIdx.x;
    int chunk = (M + 1023) / 1024;
    int b0 = t * chunk;
    int b1 = min(b0 + chunk, M);
    int v[32];   // chunk <= 32 for M <= 32768
    int s = 0;
    for (int i = b0; i < b1; i++) { v[i - b0] = bcnt[i]; s += v[i - b0]; }
    sums[t] = s;
    __syncthreads();
    for (int off = 1; off < 1024; off <<= 1) {
        int u = (t >= off) ? sums[t - off] : 0;
        __syncthreads();
        sums[t] += u;
        __syncthreads();
    }
    int run = sums[t] - s;   // exclusive prefix for this thread's chunk
    for (int i = b0; i < b1; i++) { bcnt[i] = run; run += v[i - b0]; }
    if (t == 1023) bcnt[M] = sums[1023];
}

// ---- radix CSR phase 3: scatter edges into bucket-contiguous ebuf ----------
// No global atomics: base for (bucket,block) comes from the scanned bcnt.
__global__ __launch_bounds__(512) void bscatter_kernel(const int* __restrict__ src,
                                                       const int* __restrict__ dst,
                                                       const int* __restrict__ bcnt,
                                                       uint2* __restrict__ ebuf,
                                                       int E, int nblk, int nbuck)
{
    __shared__ int cnt[128], base[128];
    int t = threadIdx.x;
    if (t < 128) cnt[t] = 0;
    __syncthreads();
    int e0 = blockIdx.x * (512 * FB_EPB);
    int s[FB_EPB], d[FB_EPB], loc[FB_EPB];
#pragma unroll
    for (int k = 0; k < FB_EPB; k++) {
        int e = e0 + k * 512 + t;
        if (e < E) {
            s[k] = src[e];
            d[k] = dst[e];
            loc[k] = atomicAdd(&cnt[d[k] >> 9], 1);
        }
    }
    __syncthreads();
    if (t < nbuck) base[t] = bcnt[t * nblk + blockIdx.x];
    __syncthreads();
#pragma unroll
    for (int k = 0; k < FB_EPB; k++) {
        int e = e0 + k * 512 + t;
        if (e < E) {
            int b = d[k] >> 9;
            ebuf[base[b] + loc[k]] = make_uint2((uint)s[k], (uint)d[k]);
        }
    }
}

// ---- radix CSR phase 4: per-bucket build rowptr + col (LDS only) -----------
__global__ __launch_bounds__(512) void pbuild_kernel(const int* __restrict__ bcnt,
                                                     const uint2* __restrict__ ebuf,
                                                     int* __restrict__ rowptr,
                                                     int* __restrict__ col,
                                                     int n, int nblk, int nbuck, int M, int E)
{
    __shared__ int lcnt[512], lscan[512];
    int t = threadIdx.x;
    int b = blockIdx.x;
    int nb = b << 9;
    int e0 = bcnt[b * nblk];
    int e1 = (b + 1 < nbuck) ? bcnt[(b + 1) * nblk] : bcnt[M];
    lcnt[t] = 0;
    __syncthreads();
    for (int i = e0 + t; i < e1; i += 512)
        atomicAdd(&lcnt[(int)ebuf[i].y - nb], 1);
    __syncthreads();
    int s = lcnt[t];
    lscan[t] = s;
    __syncthreads();
    for (int off = 1; off < 512; off <<= 1) {
        int u = (t >= off) ? lscan[t - off] : 0;
        __syncthreads();
        lscan[t] += u;
        __syncthreads();
    }
    int start = e0 + lscan[t] - s;   // exclusive
    int ncnt = min(512, n - nb);
    if (t < ncnt) rowptr[nb + t] = start;
    if (b == nbuck - 1 && t == 0) rowptr[n] = E;
    lscan[t] = start;                // reuse as cursor
    __syncthreads();
    for (int i = e0 + t; i < e1; i += 512) {
        uint2 ed = ebuf[i];
        int p = atomicAdd(&lscan[(int)ed.y - nb], 1);
        col[p] = (int)ed.x;
    }
}

// ---- gather aggregation: predicated 32-neighbor superbatches ---------------
template<bool BN>
__global__ __launch_bounds__(256) void agg_kernel(const int* __restrict__ rowptr,
                                                  const int* __restrict__ col,
                                                  const uint* __restrict__ featb,
                                                  const float* __restrict__ scsh,
                                                  uint* __restrict__ aggb, int n)
{
    int node = blockIdx.x * 4 + (threadIdx.x >> 6);
    if (node >= n) return;
    int lane = threadIdx.x & 63;
    int sub = lane >> 4, l16 = lane & 15;
    int r0 = rowptr[node], r1 = rowptr[node + 1];
    uint4* out4 = (uint4*)aggb;
    if (r0 == r1) {
        if (lane < 16) out4[(size_t)node * 16 + l16] = make_uint4(0, 0, 0, 0);
        return;
    }
    float sc[8], sh[8];
    if (BN) {
        float4 s0 = ((const float4*)scsh)[l16 * 2];
        float4 s1 = ((const float4*)scsh)[l16 * 2 + 1];
        float4 t0 = ((const float4*)scsh)[32 + l16 * 2];
        float4 t1 = ((const float4*)scsh)[32 + l16 * 2 + 1];
        sc[0] = s0.x; sc[1] = s0.y; sc[2] = s0.z; sc[3] = s0.w;
        sc[4] = s1.x; sc[5] = s1.y; sc[6] = s1.z; sc[7] = s1.w;
        sh[0] = t0.x; sh[1] = t0.y; sh[2] = t0.z; sh[3] = t0.w;
        sh[4] = t1.x; sh[5] = t1.y; sh[6] = t1.z; sh[7] = t1.w;
    }
    float acc[8] = {0.f, 0.f, 0.f, 0.f, 0.f, 0.f, 0.f, 0.f};
    const uint4* fb = (const uint4*)featb;
    int last = r1 - 1;

    for (int i = r0; i < r1; i += 32) {
        uint4 v[8];
#pragma unroll
        for (int r = 0; r < 8; r++) {
            int idx = i + r * 4 + sub;
            int c = col[min(idx, last)];
            v[r] = fb[(size_t)c * 16 + l16];
        }
#pragma unroll
        for (int r = 0; r < 8; r++) {
            bool valid = (i + r * 4 + sub) < r1;
            uint4 u = v[r];
            float e[8] = {bf_lo(u.x), bf_hi(u.x), bf_lo(u.y), bf_hi(u.y),
                          bf_lo(u.z), bf_hi(u.z), bf_lo(u.w), bf_hi(u.w)};
#pragma unroll
            for (int j = 0; j < 8; j++) {
                float t = e[j];
                if (BN) t = fmaxf(t * sc[j] + sh[j], 0.f);
                acc[j] += valid ? t : 0.f;
            }
        }
    }
#pragma unroll
    for (int j = 0; j < 8; j++) {
        acc[j] += __shfl_down(acc[j], 32);
        acc[j] += __shfl_down(acc[j], 16);
    }
    if (lane < 16) {
        float inv = 1.0f / (float)(r1 - r0);
        uint4 o;
        o.x = pack_bf16(acc[0] * inv, acc[1] * inv);
        o.y = pack_bf16(acc[2] * inv, acc[3] * inv);
        o.z = pack_bf16(acc[4] * inv, acc[5] * inv);
        o.w = pack_bf16(acc[6] * inv, acc[7] * inv);
        out4[(size_t)node * 16 + l16] = o;
    }
}

// ---- MFMA conv --------------------------------------------------------------
// FUSE1: write bf16 hb + per-block BN-stat partials (NO global atomics).
// BNP2: apply BN+ReLU inline to the p2 (root) A-fragments; write fp32 out.
#define TSTRIDE 132
template<bool FUSE1, bool BNP2>
__global__ __launch_bounds__(256) void conv_kernel(
    const uint* __restrict__ p1b, const uint* __restrict__ p2b,
    const uint* __restrict__ wb, const float* __restrict__ bias,
    const float* __restrict__ scsh, float* __restrict__ outf,
    uint* __restrict__ outb, float* __restrict__ pstats, int n)
{
    extern __shared__ float smem[];   // FUSE1: tile[64][TSTRIDE]; BNP2: scs[256]
    float* tile = smem;
    float* scs = smem;
    int w = threadIdx.x >> 6, lane = threadIdx.x & 63;
    int quad = lane >> 4, l15 = lane & 15;
    int nb = blockIdx.x * 64;

    if (BNP2) {
        scs[threadIdx.x] = scsh[threadIdx.x];
        __syncthreads();
    }

    const uint4* p1 = (const uint4*)p1b;
    const uint4* p2 = (const uint4*)p2b;
    const uint4* wv = (const uint4*)wb;

    uint4 B[8][2];
    int nt0 = w * 2;
#pragma unroll
    for (int ks = 0; ks < 8; ks++) {
#pragma unroll
        for (int t = 0; t < 2; t++)
            B[ks][t] = wv[(ks * 8 + nt0 + t) * 64 + lane];
    }

    float bv0 = bias[nt0 * 16 + l15];
    float bv1 = bias[nt0 * 16 + 16 + l15];

    for (int rt = 0; rt < 4; rt++) {
        int node = nb + rt * 16 + l15;
        int nc = min(node, n - 1);
        uint4 A[8];
#pragma unroll
        for (int ks = 0; ks < 4; ks++) A[ks] = p1[(size_t)nc * 16 + ks * 4 + quad];
#pragma unroll
        for (int ks = 0; ks < 4; ks++) A[ks + 4] = p2[(size_t)nc * 16 + ks * 4 + quad];

        if (BNP2) {
#pragma unroll
            for (int ks = 4; ks < 8; ks++) {
                int c0 = (ks - 4) * 32 + quad * 8;
                uint4 u = A[ks];
                float e[8] = {bf_lo(u.x), bf_hi(u.x), bf_lo(u.y), bf_hi(u.y),
                              bf_lo(u.z), bf_hi(u.z), bf_lo(u.w), bf_hi(u.w)};
#pragma unroll
                for (int j = 0; j < 8; j++)
                    e[j] = fmaxf(e[j] * scs[c0 + j] + scs[128 + c0 + j], 0.f);
                u.x = pack_bf16(e[0], e[1]);
                u.y = pack_bf16(e[2], e[3]);
                u.z = pack_bf16(e[4], e[5]);
                u.w = pack_bf16(e[6], e[7]);
                A[ks] = u;
            }
        }

        f32x4 acc0 = {bv0, bv0, bv0, bv0};
        f32x4 acc1 = {bv1, bv1, bv1, bv1};
#pragma unroll
        for (int ks = 0; ks < 8; ks++) {
            s16x8 a = *(s16x8*)&A[ks];
            acc0 = __builtin_amdgcn_mfma_f32_16x16x32_bf16(a, *(s16x8*)&B[ks][0], acc0, 0, 0, 0);
            acc1 = __builtin_amdgcn_mfma_f32_16x16x32_bf16(a, *(s16x8*)&B[ks][1], acc1, 0, 0, 0);
        }
        // C/D: col = lane&15, row = quad*4 + reg
        int row0 = nb + rt * 16 + quad * 4;
        int colbase = nt0 * 16 + l15;
        if (FUSE1) {
            int rloc0 = rt * 16 + quad * 4;
#pragma unroll
            for (int reg = 0; reg < 4; reg++) {
                bool ok = (row0 + reg) < n;
                tile[(rloc0 + reg) * TSTRIDE + colbase]      = ok ? acc0[reg] : 0.f;
                tile[(rloc0 + reg) * TSTRIDE + colbase + 16] = ok ? acc1[reg] : 0.f;
            }
        } else {
#pragma unroll
            for (int reg = 0; reg < 4; reg++) {
                int row = row0 + reg;
                if (row < n) {
                    outf[(size_t)row * D + colbase] = acc0[reg];
                    outf[(size_t)row * D + colbase + 16] = acc1[reg];
                }
            }
        }
    }

    if (FUSE1) {
        __syncthreads();
        // per-block column partial sums -> pstats (coalesced, no atomics)
        int colj = threadIdx.x & 127, half = threadIdx.x >> 7;
        float s = 0.f, ss = 0.f;
        for (int r = half * 32; r < half * 32 + 32; r++) {
            float v = tile[r * TSTRIDE + colj];
            s += v;
            ss += v * v;
        }
        float* pb = pstats + (size_t)blockIdx.x * 512 + half * 256;
        pb[colj] = s;
        pb[128 + colj] = ss;
        // pack tile -> bf16 hb
        uint4* ob4 = (uint4*)outb;
#pragma unroll
        for (int q4 = 0; q4 < 4; q4++) {
            int idx = q4 * 256 + threadIdx.x;   // 0..1023
            int r = idx >> 4, q = idx & 15;
            int row = nb + r;
            if (row < n) {
                float* tr = &tile[r * TSTRIDE + q * 8];
                uint4 o;
                o.x = pack_bf16(tr[0], tr[1]);
                o.y = pack_bf16(tr[2], tr[3]);
                o.z = pack_bf16(tr[4], tr[5]);
                o.w = pack_bf16(tr[6], tr[7]);
                ob4[(size_t)row * 16 + q] = o;
            }
        }
    }
}

// ---- reduce per-block stat partials into stats[256] ------------------------
__global__ __launch_bounds__(256) void reduce_kernel(const float* __restrict__ pstats,
                                                     float* __restrict__ stats, int nparts)
{
    int j = threadIdx.x;
    int chunk = (nparts + gridDim.x - 1) / gridDim.x;
    int p0 = blockIdx.x * chunk;
    int p1 = min(p0 + chunk, nparts);
    float s = 0.f;
    for (int p = p0; p < p1; p++) s += pstats[(size_t)p * 256 + j];
    unsafeAtomicAdd(&stats[j], s);
}

// ---- BN scale/shift from stats ---------------------------------------------
__global__ void bnfin_kernel(const float* __restrict__ stats, const float* __restrict__ gamma,
                             const float* __restrict__ beta, float* __restrict__ scsh, float n_inv)
{
    int j = threadIdx.x;
    float mean = stats[j] * n_inv;
    float var = fmaxf(stats[128 + j] * n_inv - mean * mean, 0.f);
    float sc = gamma[j] * rsqrtf(var + EPS);
    scsh[j] = sc;
    scsh[128 + j] = beta[j] - mean * sc;
}

extern "C" void kernel_launch(void* const* d_in, const int* in_sizes, int n_in,
                              void* d_out, int out_size, void* d_ws, size_t ws_size,
                              hipStream_t stream)
{
    const float* x     = (const float*)d_in[0];
    const int*   ei    = (const int*)d_in[1];
    const float* w1_l  = (const float*)d_in[2];
    const float* b1_l  = (const float*)d_in[3];
    const float* w1_r  = (const float*)d_in[4];
    const float* w2_l  = (const float*)d_in[5];
    const float* b2_l  = (const float*)d_in[6];
    const float* w2_r  = (const float*)d_in[7];
    const float* gamma = (const float*)d_in[8];
    const float* beta  = (const float*)d_in[9];

    int N = in_sizes[0] / D;
    int E = in_sizes[1] / 2;
    const int* src = ei;
    const int* dst = ei + E;

    int cblocks = (N + 63) / 64;
    int nbuck   = (N + 511) >> 9;               // 98
    int nblk    = (E + 4095) / 4096;            // 196
    int M       = nbuck * nblk;                 // 19208

    // workspace layout:
    // uints: aggb[N*64] | xb[N*64] | hb[N*64] | wb1[16384] | wb2[16384]
    // uint2: ebuf[E]
    // floats: stats[256] | scsh[256] | pstats[cblocks*512]
    // ints: rowptr[N+1] | col[E] | bcnt[M+1]
    uint*  aggb   = (uint*)d_ws;
    uint*  xb     = aggb + (size_t)N * 64;
    uint*  hb     = xb + (size_t)N * 64;
    uint*  wb1    = hb + (size_t)N * 64;
    uint*  wb2    = wb1 + 16384;
    uint2* ebuf   = (uint2*)(wb2 + 16384);
    float* stats  = (float*)(ebuf + E);
    float* scsh   = stats + 256;
    float* pstats = scsh + 256;
    int*   rowptr = (int*)(pstats + (size_t)cblocks * 512);
    int*   col    = rowptr + N + 1;
    int*   bcnt   = col + E;

    hipMemsetAsync(stats, 0, 256 * sizeof(float), stream);

    int ncvt = N * 32;
    int pblocks = (ncvt + 8192 + 255) / 256;
    prep_kernel<<<pblocks, 256, 0, stream>>>(x, xb, ncvt, w1_l, w1_r, w2_l, w2_r, wb1, wb2);

    int ablocks = (N + 3) / 4;

    // CSR build: radix partition, zero global atomics
    bcount_kernel<<<nblk, 512, 0, stream>>>(dst, bcnt, E, nblk, nbuck);
    bscan_kernel<<<1, 1024, 0, stream>>>(bcnt, M);
    bscatter_kernel<<<nblk, 512, 0, stream>>>(src, dst, bcnt, ebuf, E, nblk, nbuck);
    pbuild_kernel<<<nbuck, 512, 0, stream>>>(bcnt, ebuf, rowptr, col, N, nblk, nbuck, M, E);

    // layer 1: agg + conv (conv writes bf16 hb and per-block BN-stat partials)
    agg_kernel<false><<<ablocks, 256, 0, stream>>>(rowptr, col, xb, nullptr, aggb, N);
    conv_kernel<true, false><<<cblocks, 256, 64 * TSTRIDE * 4, stream>>>(
        aggb, xb, wb1, b1_l, nullptr, nullptr, hb, pstats, N);

    // reduce partials, then BN scale/shift
    reduce_kernel<<<32, 256, 0, stream>>>(pstats, stats, cblocks * 2);
    bnfin_kernel<<<1, 128, 0, stream>>>(stats, gamma, beta, scsh, 1.0f / (float)N);

    // layer 2: agg applies BN+ReLU inline; conv applies BN+ReLU to root term
    agg_kernel<true><<<ablocks, 256, 0, stream>>>(rowptr, col, hb, scsh, aggb, N);
    conv_kernel<false, true><<<cblocks, 256, 256 * 4, stream>>>(
        aggb, hb, wb2, b2_l, scsh, (float*)d_out, nullptr, nullptr, N);
}

// Round 11
// 252.461 us; speedup vs baseline: 1.1530x; 1.0504x over previous
//
#include <hip/hip_runtime.h>

#define D 128
#define EPS 1e-5f
#define FB_EPB 8   // edges per thread in bcount/bscatter (512 thr -> 4096 edges/block)

typedef unsigned int uint;
typedef __attribute__((ext_vector_type(4))) float f32x4;
typedef __attribute__((ext_vector_type(8))) short s16x8;

// ---- bf16 pack/unpack helpers (RTNE) ---------------------------------------
__device__ __forceinline__ uint pack_bf16(float a, float b)
{
    uint ua = __float_as_uint(a);
    uint ub = __float_as_uint(b);
    ua += 0x7FFFu + ((ua >> 16) & 1u);
    ub += 0x7FFFu + ((ub >> 16) & 1u);
    return (ua >> 16) | (ub & 0xFFFF0000u);
}
__device__ __forceinline__ float bf_lo(uint v) { return __uint_as_float(v << 16); }
__device__ __forceinline__ float bf_hi(uint v) { return __uint_as_float(v & 0xFFFF0000u); }

// ---- prep: x -> xb (bf16, + zero row N) AND wb1/wb2 (MFMA B-frag order) ----
__global__ void prep_kernel(const float* __restrict__ x, uint* __restrict__ xb, int ncvt,
                            const float* __restrict__ w1l, const float* __restrict__ w1r,
                            const float* __restrict__ w2l, const float* __restrict__ w2r,
                            uint* __restrict__ wb1, uint* __restrict__ wb2)
{
    int idx = blockIdx.x * 256 + threadIdx.x;
    if (idx < ncvt) {
        float4 v = ((const float4*)x)[idx];
        uint2 o;
        o.x = pack_bf16(v.x, v.y);
        o.y = pack_bf16(v.z, v.w);
        ((uint2*)xb)[idx] = o;
    } else if (idx < ncvt + 8192) {
        int r = idx - ncvt;          // 0..8191
        int layer = r >> 12;
        int rem = r & 4095;
        int lane = rem & 63;
        int knt = rem >> 6;
        int kstep = knt >> 3, nt = knt & 7;
        int nn = nt * 16 + (lane & 15);
        int kbase = kstep * 32 + (lane >> 4) * 8;
        const float* wl = layer ? w2l : w1l;
        const float* wr = layer ? w2r : w1r;
        uint* wb = layer ? wb2 : wb1;
        float v[8];
#pragma unroll
        for (int j = 0; j < 8; j++) {
            int k = kbase + j;
            v[j] = (k < D) ? wl[nn * D + k] : wr[nn * D + (k - D)];
        }
        uint4 o;
        o.x = pack_bf16(v[0], v[1]);
        o.y = pack_bf16(v[2], v[3]);
        o.z = pack_bf16(v[4], v[5]);
        o.w = pack_bf16(v[6], v[7]);
        ((uint4*)wb)[(kstep * 8 + nt) * 64 + lane] = o;
    } else if (idx < ncvt + 8192 + 32) {
        // zero row (index N) for invalid-slot gathers
        ((uint2*)xb)[ncvt + (idx - ncvt - 8192)] = make_uint2(0, 0);
    }
}

// ---- radix CSR phase 1: per-(block,bucket) edge counts ----------------------
__global__ __launch_bounds__(512) void bcount_kernel(const int* __restrict__ dst,
                                                     int* __restrict__ bcnt,
                                                     int E, int nblk, int nbuck)
{
    __shared__ int cnt[128];
    int t = threadIdx.x;
    if (t < 128) cnt[t] = 0;
    __syncthreads();
    int e0 = blockIdx.x * (512 * FB_EPB);
#pragma unroll
    for (int k = 0; k < FB_EPB; k++) {
        int e = e0 + k * 512 + t;
        if (e < E) atomicAdd(&cnt[dst[e] >> 9], 1);
    }
    __syncthreads();
    if (t < nbuck) bcnt[t * nblk + blockIdx.x] = cnt[t];
}

// ---- radix CSR phase 2: single-block exclusive scan of bcnt[M], append total
__global__ __launch_bounds__(1024) void bscan_kernel(int* __restrict__ bcnt, int M)
{
    __shared__ int sums[1024];
    int t = threadIdx.x;
    int chunk = (M + 1023) / 1024;
    int b0 = t * chunk;
    int b1 = min(b0 + chunk, M);
    int v[32];
    int s = 0;
    for (int i = b0; i < b1; i++) { v[i - b0] = bcnt[i]; s += v[i - b0]; }
    sums[t] = s;
    __syncthreads();
    for (int off = 1; off < 1024; off <<= 1) {
        int u = (t >= off) ? sums[t - off] : 0;
        __syncthreads();
        sums[t] += u;
        __syncthreads();
    }
    int run = sums[t] - s;
    for (int i = b0; i < b1; i++) { bcnt[i] = run; run += v[i - b0]; }
    if (t == 1023) bcnt[M] = sums[1023];
}

// ---- radix CSR phase 3: scatter edges into bucket-contiguous ebuf ----------
__global__ __launch_bounds__(512) void bscatter_kernel(const int* __restrict__ src,
                                                       const int* __restrict__ dst,
                                                       const int* __restrict__ bcnt,
                                                       uint2* __restrict__ ebuf,
                                                       int E, int nblk, int nbuck)
{
    __shared__ int cnt[128], base[128];
    int t = threadIdx.x;
    if (t < 128) cnt[t] = 0;
    __syncthreads();
    int e0 = blockIdx.x * (512 * FB_EPB);
    int s[FB_EPB], d[FB_EPB], loc[FB_EPB];
#pragma unroll
    for (int k = 0; k < FB_EPB; k++) {
        int e = e0 + k * 512 + t;
        if (e < E) {
            s[k] = src[e];
            d[k] = dst[e];
            loc[k] = atomicAdd(&cnt[d[k] >> 9], 1);
        }
    }
    __syncthreads();
    if (t < nbuck) base[t] = bcnt[t * nblk + blockIdx.x];
    __syncthreads();
#pragma unroll
    for (int k = 0; k < FB_EPB; k++) {
        int e = e0 + k * 512 + t;
        if (e < E) {
            int b = d[k] >> 9;
            ebuf[base[b] + loc[k]] = make_uint2((uint)s[k], (uint)d[k]);
        }
    }
}

// ---- radix CSR phase 4: per-bucket build rowptr + col (LDS only) -----------
__global__ __launch_bounds__(512) void pbuild_kernel(const int* __restrict__ bcnt,
                                                     const uint2* __restrict__ ebuf,
                                                     int* __restrict__ rowptr,
                                                     int* __restrict__ col,
                                                     int n, int nblk, int nbuck, int M, int E)
{
    __shared__ int lcnt[512], lscan[512];
    int t = threadIdx.x;
    int b = blockIdx.x;
    int nb = b << 9;
    int e0 = bcnt[b * nblk];
    int e1 = (b + 1 < nbuck) ? bcnt[(b + 1) * nblk] : bcnt[M];
    lcnt[t] = 0;
    __syncthreads();
    for (int i = e0 + t; i < e1; i += 512)
        atomicAdd(&lcnt[(int)ebuf[i].y - nb], 1);
    __syncthreads();
    int s = lcnt[t];
    lscan[t] = s;
    __syncthreads();
    for (int off = 1; off < 512; off <<= 1) {
        int u = (t >= off) ? lscan[t - off] : 0;
        __syncthreads();
        lscan[t] += u;
        __syncthreads();
    }
    int start = e0 + lscan[t] - s;
    int ncnt = min(512, n - nb);
    if (t < ncnt) rowptr[nb + t] = start;
    if (b == nbuck - 1 && t == 0) rowptr[n] = E;
    lscan[t] = start;
    __syncthreads();
    for (int i = e0 + t; i < e1; i += 512) {
        uint2 ed = ebuf[i];
        int p = atomicAdd(&lscan[(int)ed.y - nb], 1);
        col[p] = (int)ed.x;
    }
}

// ---- gather aggregation: 16-neighbor batches, zero-row padding, no BN ------
// Wave per node; lane = sub*16 + l16. All loads unconditional (invalid slots
// gather the zero row at index zrow=N), so the inner loop is pure unpack+add.
__global__ __launch_bounds__(256) void agg_kernel(const int* __restrict__ rowptr,
                                                  const int* __restrict__ col,
                                                  const uint* __restrict__ featb,
                                                  uint* __restrict__ aggb, int n)
{
    int node = blockIdx.x * 4 + (threadIdx.x >> 6);
    if (node >= n) return;
    int lane = threadIdx.x & 63;
    int sub = lane >> 4, l16 = lane & 15;
    int r0 = rowptr[node], r1 = rowptr[node + 1];
    uint4* out4 = (uint4*)aggb;
    if (r0 == r1) {
        if (lane < 16) out4[(size_t)node * 16 + l16] = make_uint4(0, 0, 0, 0);
        return;
    }
    float acc[8] = {0.f, 0.f, 0.f, 0.f, 0.f, 0.f, 0.f, 0.f};
    const uint4* fb = (const uint4*)featb;
    int last = r1 - 1;

    for (int i = r0; i < r1; i += 16) {
        uint4 v[4];
#pragma unroll
        for (int r = 0; r < 4; r++) {
            int idx = i + r * 4 + sub;
            int cl = col[min(idx, last)];
            int c = (idx < r1) ? cl : n;       // n = zero row
            v[r] = fb[(size_t)c * 16 + l16];
        }
#pragma unroll
        for (int r = 0; r < 4; r++) {
            uint4 u = v[r];
            acc[0] += bf_lo(u.x); acc[1] += bf_hi(u.x);
            acc[2] += bf_lo(u.y); acc[3] += bf_hi(u.y);
            acc[4] += bf_lo(u.z); acc[5] += bf_hi(u.z);
            acc[6] += bf_lo(u.w); acc[7] += bf_hi(u.w);
        }
    }
#pragma unroll
    for (int j = 0; j < 8; j++) {
        acc[j] += __shfl_down(acc[j], 32);
        acc[j] += __shfl_down(acc[j], 16);
    }
    if (lane < 16) {
        float inv = 1.0f / (float)(r1 - r0);
        uint4 o;
        o.x = pack_bf16(acc[0] * inv, acc[1] * inv);
        o.y = pack_bf16(acc[2] * inv, acc[3] * inv);
        o.z = pack_bf16(acc[4] * inv, acc[5] * inv);
        o.w = pack_bf16(acc[6] * inv, acc[7] * inv);
        out4[(size_t)node * 16 + l16] = o;
    }
}

// ---- MFMA conv --------------------------------------------------------------
// FUSE1: write bf16 hb + per-block BN-stat partials (NO global atomics).
#define TSTRIDE 132
template<bool FUSE1>
__global__ __launch_bounds__(256) void conv_kernel(
    const uint* __restrict__ p1b, const uint* __restrict__ p2b,
    const uint* __restrict__ wb, const float* __restrict__ bias,
    float* __restrict__ outf, uint* __restrict__ outb,
    float* __restrict__ pstats, int n)
{
    extern __shared__ float smem[];   // FUSE1: tile[64][TSTRIDE]
    float* tile = smem;
    int w = threadIdx.x >> 6, lane = threadIdx.x & 63;
    int quad = lane >> 4, l15 = lane & 15;
    int nb = blockIdx.x * 64;

    const uint4* p1 = (const uint4*)p1b;
    const uint4* p2 = (const uint4*)p2b;
    const uint4* wv = (const uint4*)wb;

    uint4 B[8][2];
    int nt0 = w * 2;
#pragma unroll
    for (int ks = 0; ks < 8; ks++) {
#pragma unroll
        for (int t = 0; t < 2; t++)
            B[ks][t] = wv[(ks * 8 + nt0 + t) * 64 + lane];
    }

    float bv0 = bias[nt0 * 16 + l15];
    float bv1 = bias[nt0 * 16 + 16 + l15];

    for (int rt = 0; rt < 4; rt++) {
        int node = nb + rt * 16 + l15;
        int nc = min(node, n - 1);
        uint4 A[8];
#pragma unroll
        for (int ks = 0; ks < 4; ks++) A[ks] = p1[(size_t)nc * 16 + ks * 4 + quad];
#pragma unroll
        for (int ks = 0; ks < 4; ks++) A[ks + 4] = p2[(size_t)nc * 16 + ks * 4 + quad];

        f32x4 acc0 = {bv0, bv0, bv0, bv0};
        f32x4 acc1 = {bv1, bv1, bv1, bv1};
#pragma unroll
        for (int ks = 0; ks < 8; ks++) {
            s16x8 a = *(s16x8*)&A[ks];
            acc0 = __builtin_amdgcn_mfma_f32_16x16x32_bf16(a, *(s16x8*)&B[ks][0], acc0, 0, 0, 0);
            acc1 = __builtin_amdgcn_mfma_f32_16x16x32_bf16(a, *(s16x8*)&B[ks][1], acc1, 0, 0, 0);
        }
        // C/D: col = lane&15, row = quad*4 + reg
        int row0 = nb + rt * 16 + quad * 4;
        int colbase = nt0 * 16 + l15;
        if (FUSE1) {
            int rloc0 = rt * 16 + quad * 4;
#pragma unroll
            for (int reg = 0; reg < 4; reg++) {
                bool ok = (row0 + reg) < n;
                tile[(rloc0 + reg) * TSTRIDE + colbase]      = ok ? acc0[reg] : 0.f;
                tile[(rloc0 + reg) * TSTRIDE + colbase + 16] = ok ? acc1[reg] : 0.f;
            }
        } else {
#pragma unroll
            for (int reg = 0; reg < 4; reg++) {
                int row = row0 + reg;
                if (row < n) {
                    outf[(size_t)row * D + colbase] = acc0[reg];
                    outf[(size_t)row * D + colbase + 16] = acc1[reg];
                }
            }
        }
    }

    if (FUSE1) {
        __syncthreads();
        int colj = threadIdx.x & 127, half = threadIdx.x >> 7;
        float s = 0.f, ss = 0.f;
        for (int r = half * 32; r < half * 32 + 32; r++) {
            float v = tile[r * TSTRIDE + colj];
            s += v;
            ss += v * v;
        }
        float* pb = pstats + (size_t)blockIdx.x * 512 + half * 256;
        pb[colj] = s;
        pb[128 + colj] = ss;
        uint4* ob4 = (uint4*)outb;
#pragma unroll
        for (int q4 = 0; q4 < 4; q4++) {
            int idx = q4 * 256 + threadIdx.x;
            int r = idx >> 4, q = idx & 15;
            int row = nb + r;
            if (row < n) {
                float* tr = &tile[r * TSTRIDE + q * 8];
                uint4 o;
                o.x = pack_bf16(tr[0], tr[1]);
                o.y = pack_bf16(tr[2], tr[3]);
                o.z = pack_bf16(tr[4], tr[5]);
                o.w = pack_bf16(tr[6], tr[7]);
                ob4[(size_t)row * 16 + q] = o;
            }
        }
    }
}

// ---- reduce per-block stat partials into stats[256] ------------------------
__global__ __launch_bounds__(256) void reduce_kernel(const float* __restrict__ pstats,
                                                     float* __restrict__ stats, int nparts)
{
    int j = threadIdx.x;
    int chunk = (nparts + gridDim.x - 1) / gridDim.x;
    int p0 = blockIdx.x * chunk;
    int p1 = min(p0 + chunk, nparts);
    float s = 0.f;
    for (int p = p0; p < p1; p++) s += pstats[(size_t)p * 256 + j];
    unsafeAtomicAdd(&stats[j], s);
}

// ---- BN scale/shift from stats ---------------------------------------------
__global__ void bnfin_kernel(const float* __restrict__ stats, const float* __restrict__ gamma,
                             const float* __restrict__ beta, float* __restrict__ scsh, float n_inv)
{
    int j = threadIdx.x;
    float mean = stats[j] * n_inv;
    float var = fmaxf(stats[128 + j] * n_inv - mean * mean, 0.f);
    float sc = gamma[j] * rsqrtf(var + EPS);
    scsh[j] = sc;
    scsh[128 + j] = beta[j] - mean * sc;
}

// ---- bnapply: hbn = relu(hb*sc+sh) (bf16 -> bf16), + zero row N ------------
__global__ __launch_bounds__(256) void bnapply_kernel(const uint* __restrict__ hb,
                                                      const float* __restrict__ scsh,
                                                      uint* __restrict__ hbn, int total2)
{
    __shared__ float scs[256];
    scs[threadIdx.x] = scsh[threadIdx.x];
    __syncthreads();
    int idx = blockIdx.x * 256 + threadIdx.x;
    if (blockIdx.x == 0 && threadIdx.x < 32)
        ((uint2*)hbn)[total2 + threadIdx.x] = make_uint2(0, 0);   // zero row
    if (idx >= total2) return;
    int j4 = (idx & 31) * 4;
    uint2 u = ((const uint2*)hb)[idx];
    float e0 = fmaxf(bf_lo(u.x) * scs[j4 + 0] + scs[128 + j4 + 0], 0.f);
    float e1 = fmaxf(bf_hi(u.x) * scs[j4 + 1] + scs[128 + j4 + 1], 0.f);
    float e2 = fmaxf(bf_lo(u.y) * scs[j4 + 2] + scs[128 + j4 + 2], 0.f);
    float e3 = fmaxf(bf_hi(u.y) * scs[j4 + 3] + scs[128 + j4 + 3], 0.f);
    uint2 o;
    o.x = pack_bf16(e0, e1);
    o.y = pack_bf16(e2, e3);
    ((uint2*)hbn)[idx] = o;
}

extern "C" void kernel_launch(void* const* d_in, const int* in_sizes, int n_in,
                              void* d_out, int out_size, void* d_ws, size_t ws_size,
                              hipStream_t stream)
{
    const float* x     = (const float*)d_in[0];
    const int*   ei    = (const int*)d_in[1];
    const float* w1_l  = (const float*)d_in[2];
    const float* b1_l  = (const float*)d_in[3];
    const float* w1_r  = (const float*)d_in[4];
    const float* w2_l  = (const float*)d_in[5];
    const float* b2_l  = (const float*)d_in[6];
    const float* w2_r  = (const float*)d_in[7];
    const float* gamma = (const float*)d_in[8];
    const float* beta  = (const float*)d_in[9];

    int N = in_sizes[0] / D;
    int E = in_sizes[1] / 2;
    const int* src = ei;
    const int* dst = ei + E;

    int cblocks = (N + 63) / 64;
    int nbuck   = (N + 511) >> 9;               // 98
    int nblk    = (E + 4095) / 4096;            // 196
    int M       = nbuck * nblk;                 // 19208

    // workspace layout:
    // uints: aggb[N*64] | xb[(N+1)*64] | hb[N*64] | hbn[(N+1)*64] | wb1/wb2
    // uint2: ebuf[E]; floats: stats|scsh|pstats; ints: rowptr|col|bcnt
    uint*  aggb   = (uint*)d_ws;
    uint*  xb     = aggb + (size_t)N * 64;
    uint*  hb     = xb + (size_t)(N + 1) * 64;
    uint*  hbn    = hb + (size_t)N * 64;
    uint*  wb1    = hbn + (size_t)(N + 1) * 64;
    uint*  wb2    = wb1 + 16384;
    uint2* ebuf   = (uint2*)(wb2 + 16384);
    float* stats  = (float*)(ebuf + E);
    float* scsh   = stats + 256;
    float* pstats = scsh + 256;
    int*   rowptr = (int*)(pstats + (size_t)cblocks * 512);
    int*   col    = rowptr + N + 1;
    int*   bcnt   = col + E;

    hipMemsetAsync(stats, 0, 256 * sizeof(float), stream);

    int ncvt = N * 32;
    int pblocks = (ncvt + 8192 + 32 + 255) / 256;
    prep_kernel<<<pblocks, 256, 0, stream>>>(x, xb, ncvt, w1_l, w1_r, w2_l, w2_r, wb1, wb2);

    int ablocks = (N + 3) / 4;

    // CSR build: radix partition, zero global atomics
    bcount_kernel<<<nblk, 512, 0, stream>>>(dst, bcnt, E, nblk, nbuck);
    bscan_kernel<<<1, 1024, 0, stream>>>(bcnt, M);
    bscatter_kernel<<<nblk, 512, 0, stream>>>(src, dst, bcnt, ebuf, E, nblk, nbuck);
    pbuild_kernel<<<nbuck, 512, 0, stream>>>(bcnt, ebuf, rowptr, col, N, nblk, nbuck, M, E);

    // layer 1
    agg_kernel<<<ablocks, 256, 0, stream>>>(rowptr, col, xb, aggb, N);
    conv_kernel<true><<<cblocks, 256, 64 * TSTRIDE * 4, stream>>>(
        aggb, xb, wb1, b1_l, nullptr, hb, pstats, N);

    // BN
    reduce_kernel<<<32, 256, 0, stream>>>(pstats, stats, cblocks * 2);
    bnfin_kernel<<<1, 128, 0, stream>>>(stats, gamma, beta, scsh, 1.0f / (float)N);
    bnapply_kernel<<<(N * 32 + 255) / 256, 256, 0, stream>>>(hb, scsh, hbn, N * 32);

    // layer 2
    agg_kernel<<<ablocks, 256, 0, stream>>>(rowptr, col, hbn, aggb, N);
    conv_kernel<false><<<cblocks, 256, 1024, stream>>>(
        aggb, hbn, wb2, b2_l, (float*)d_out, nullptr, nullptr, N);
}